// Round 2
// baseline (279.642 us; speedup 1.0000x reference)
//
#include <hip/hip_runtime.h>
#include <stdint.h>

// Problem constants (B=1)
#define L_SEQ 2048
#define DMODEL 1024
#define DI_DIM 2048
#define NSSM 16
#define NPROJ 2080        // DI + 2N
#define NCHUNK 64
#define LCHUNK 32         // NCHUNK*LCHUNK == L_SEQ

typedef __attribute__((ext_vector_type(8))) short bf16x8;
typedef __attribute__((ext_vector_type(8))) unsigned short u16x8;
typedef __attribute__((ext_vector_type(4))) float f32x4;

__device__ __forceinline__ float bf2f(unsigned short u) {
  union { uint32_t u; float f; } v; v.u = (uint32_t)u << 16; return v.f;
}
__device__ __forceinline__ unsigned short f2bf(float f) {
  union { float f; uint32_t u; } v; v.f = f;
  uint32_t u = v.u;
  return (unsigned short)((u + 0x7fffu + ((u >> 16) & 1u)) >> 16);
}
__device__ __forceinline__ void async16(const void* g, void* l) {
  __builtin_amdgcn_global_load_lds(
      (__attribute__((address_space(1))) void*)(g),
      (__attribute__((address_space(3))) void*)(l), 16, 0, 0);
}
// native-op math (libm log1pf/fdiv expand to huge sequences w/o fast-math;
// switching to __logf/__expf/rcp collapsed scan kernels ~3x -- r7 measured)
__device__ __forceinline__ float softplusf(float p) {
  return (p > 20.f) ? p : __logf(1.f + __expf(p));
}
__device__ __forceinline__ float siluf(float x) {
  return x * __builtin_amdgcn_rcpf(1.f + __expf(-x));
}

// counted-vmcnt sync primitives (kept from r1: measured neutral vs __syncthreads,
// confirming m131-m140 "source pipelining is null on this structure").
#define WAITV(N) asm volatile("s_waitcnt vmcnt(" #N ")" ::: "memory")
#define GBAR()                                   \
  {                                              \
    __builtin_amdgcn_s_barrier();                \
    asm volatile("" ::: "memory");               \
  }

// ---------------- fused f32 -> bf16 converts (x, W_in, W_x) ----------------
#define CVT_N1 524288                    // x:    2048*1024/4
#define CVT_N2 (CVT_N1 + 1048576)        // W_in: 4096*1024/4
#define CVT_N3 (CVT_N2 + 1064960)        // W_x:  2080*2048/4
__global__ void k_convert3(const float* __restrict__ x, const float* __restrict__ win,
                           const float* __restrict__ wx, unsigned short* __restrict__ xb,
                           unsigned short* __restrict__ winb, unsigned short* __restrict__ wxb) {
  int i = blockIdx.x * 256 + threadIdx.x;
  const float4* src; unsigned short* dst; int j;
  if (i < CVT_N1)      { src = (const float4*)x;   dst = xb;   j = i; }
  else if (i < CVT_N2) { src = (const float4*)win; dst = winb; j = i - CVT_N1; }
  else if (i < CVT_N3) { src = (const float4*)wx;  dst = wxb;  j = i - CVT_N2; }
  else return;
  float4 v = src[j];
  ushort4 o;
  o.x = f2bf(v.x); o.y = f2bf(v.y); o.z = f2bf(v.z); o.w = f2bf(v.w);
  ((ushort4*)dst)[j] = o;
}

__global__ void k_f32_to_bf16(const float* __restrict__ in,
                              unsigned short* __restrict__ out, int n4) {
  int i = blockIdx.x * blockDim.x + threadIdx.x;
  if (i < n4) {
    const float4 v = ((const float4*)in)[i];
    ushort4 o;
    o.x = f2bf(v.x); o.y = f2bf(v.y); o.z = f2bf(v.z); o.w = f2bf(v.w);
    ((ushort4*)out)[i] = o;
  }
}

// ---------------- bf16 N-T GEMM: C = A[M,K] * B[N,K]^T (+bias) ----------------
// TM=64 x 128 tile, 32-K steps, DEPTH-deep LDS ring, counted vmcnt + raw barrier.
// r1 A/B: counted-vmcnt ring == __syncthreads (null) -> K-loop latency is NOT
// the constraint; OccupancyPercent 18% (2.1 blocks/CU grid) is. This round:
// split-K to raise grid to 4 blocks/CU (occupancy is the m102 N=2048 limiter).
// Factor status from earlier A/B (all retained): atomics -40% | uncoalesced
// staging -60% | TM=32 compute dilution -25% | row-major LDS conflicts -11%
// | XOR-swizzle staging/reads verified, 0 bank conflicts.
// Split-K partials: block z's C base = (z < zAlt) ? C + z*M*N : Calt + (z-zAlt)*M*N
// (lets partial slabs live in two disjoint workspace regions). gridDim.z>1: no bias.
template <typename OutT, int DEPTH>
__global__ __launch_bounds__(256) void k_gemm_bt(
    const unsigned short* __restrict__ A, const unsigned short* __restrict__ B,
    const float* __restrict__ bias, OutT* __restrict__ C,
    OutT* __restrict__ Calt, int zAlt,
    int M, int N, int K) {
  __shared__ unsigned short As[DEPTH][64 * 32];
  __shared__ unsigned short Bs[DEPTH][128 * 32];
  const int tid = threadIdx.x;
  const int wave = tid >> 6;
  const int lane = tid & 63;
  const int m0 = blockIdx.y * 64;
  const int n0 = blockIdx.x * 128;
  const int kLen = K / gridDim.z;
  const int kLo = blockIdx.z * kLen;

  // staging source: lane l -> row l>>2, kgroup (l&3)^((l>>3)&3)  (swizzled)
  const int srow = lane >> 2;
  const int scol = ((lane & 3) ^ ((lane >> 3) & 3)) * 8;
  int ar = m0 + wave * 16 + srow;         if (ar > M - 1) ar = M - 1;
  int br0 = n0 + wave * 32 + srow;        if (br0 > N - 1) br0 = N - 1;
  int br1 = n0 + wave * 32 + 16 + srow;   if (br1 > N - 1) br1 = N - 1;
  const unsigned short* ap  = A + (size_t)ar * K + scol + kLo;
  const unsigned short* bp0 = B + (size_t)br0 * K + scol + kLo;
  const unsigned short* bp1 = B + (size_t)br1 * K + scol + kLo;
  const int soA  = wave * 512;
  const int soB0 = (wave * 2) * 512;
  const int soB1 = (wave * 2 + 1) * 512;

  // compute-side fragment read: block_base + mrow*32 + swz8 (ushorts)
  const int mrow = lane & 15;
  const int swz8 = (((lane >> 4) ^ ((mrow >> 1) & 3)) * 8);
  const int ro = mrow * 32 + swz8;

  f32x4 acc[4][2];
#pragma unroll
  for (int i = 0; i < 4; i++)
#pragma unroll
    for (int j = 0; j < 2; j++) acc[i][j] = (f32x4){0.f, 0.f, 0.f, 0.f};

  const int niter = kLen / 32;

#define STAGE(BUF, KT)                                                         \
  {                                                                            \
    async16(ap + (KT), &As[BUF][soA]);                                         \
    async16(bp0 + (KT), &Bs[BUF][soB0]);                                       \
    async16(bp1 + (KT), &Bs[BUF][soB1]);                                       \
  }

#define GEMM_COMPUTE(BUF)                                                      \
  {                                                                            \
    bf16x8 af[4], bfv[2];                                                      \
    _Pragma("unroll")                                                          \
    for (int i = 0; i < 4; i++)                                                \
      af[i] = *(const bf16x8*)&As[BUF][i * 512 + ro];                          \
    _Pragma("unroll")                                                          \
    for (int j = 0; j < 2; j++)                                                \
      bfv[j] = *(const bf16x8*)&Bs[BUF][(wave * 2 + j) * 512 + ro];            \
    _Pragma("unroll")                                                          \
    for (int i = 0; i < 4; i++)                                                \
      _Pragma("unroll")                                                        \
      for (int j = 0; j < 2; j++)                                              \
        acc[i][j] = __builtin_amdgcn_mfma_f32_16x16x32_bf16(af[i], bfv[j],     \
                                                        acc[i][j], 0, 0, 0);   \
  }

  // prologue: fill DEPTH-1 ring slots ( (DEPTH-1)*3 loads in flight )
#pragma unroll
  for (int j = 0; j < DEPTH - 1; j++) STAGE(j, j * 32)

  int cur = 0, nxt = DEPTH - 1;
  for (int t = 0; t < niter - (DEPTH - 1); t++) {
    if constexpr (DEPTH == 4) { WAITV(6); } else { WAITV(3); }
    GBAR()
    STAGE(nxt, (t + DEPTH - 1) * 32)
    GEMM_COMPUTE(cur)
    cur = (cur == DEPTH - 1) ? 0 : cur + 1;
    nxt = (nxt == DEPTH - 1) ? 0 : nxt + 1;
  }
  // epilogue: drain the last DEPTH-1 slots with decreasing waits
  if constexpr (DEPTH == 4) {
    WAITV(6); GBAR()
    GEMM_COMPUTE(cur) cur = (cur == 3) ? 0 : cur + 1;
    WAITV(3); GBAR()
    GEMM_COMPUTE(cur) cur = (cur == 3) ? 0 : cur + 1;
    WAITV(0); GBAR()
    GEMM_COMPUTE(cur)
  } else {
    WAITV(3); GBAR()
    GEMM_COMPUTE(cur) cur = (cur == DEPTH - 1) ? 0 : cur + 1;
    WAITV(0); GBAR()
    GEMM_COMPUTE(cur)
  }
#undef STAGE
#undef GEMM_COMPUTE

  // epilogue: C/D layout col=lane&15, row=(lane>>4)*4+reg (verified mapping)
  const bool withBias = (gridDim.z == 1);
  const int bz = blockIdx.z;
  OutT* Cz = (bz < zAlt) ? (C + (size_t)bz * ((size_t)M * N))
                         : (Calt + (size_t)(bz - zAlt) * ((size_t)M * N));
#pragma unroll
  for (int j = 0; j < 2; j++) {
    int col = n0 + wave * 32 + j * 16 + (lane & 15);
    if (col < N) {
      float bv = withBias ? bias[col] : 0.f;
#pragma unroll
      for (int i = 0; i < 4; i++) {
        int rbase = m0 + i * 16 + (lane >> 4) * 4;
#pragma unroll
        for (int r = 0; r < 4; r++) {
          float v = acc[i][j][r] + bv;
          if constexpr (sizeof(OutT) == 2)
            Cz[(size_t)(rbase + r) * N + col] = (OutT)f2bf(v);
          else
            Cz[(size_t)(rbase + r) * N + col] = (OutT)v;
        }
      }
    }
  }
}

// ---------------- split-K=4 reduce: out = p0+p1+p2+p3 + bias ----------------
// p holds slabs z0..z2 contiguously; pz3 is the alt slab.
__global__ void k_reduce_out4(const float* __restrict__ p, const float* __restrict__ pz3,
                              const float* __restrict__ bias, float* __restrict__ out) {
  int i = blockIdx.x * 256 + threadIdx.x;   // float4 index over 2048*1024
  const int N4 = L_SEQ * DMODEL / 4;
  float4 a = ((const float4*)p)[i];
  float4 b = ((const float4*)p)[i + N4];
  float4 c = ((const float4*)p)[i + 2 * N4];
  float4 d = ((const float4*)pz3)[i];
  int col = (i * 4) & (DMODEL - 1);
  float4 bb = *(const float4*)&bias[col];
  float4 o;
  o.x = a.x + b.x + c.x + d.x + bb.x;
  o.y = a.y + b.y + c.y + d.y + bb.y;
  o.z = a.z + b.z + c.z + d.z + bb.z;
  o.w = a.w + b.w + c.w + d.w + bb.w;
  ((float4*)out)[i] = o;
}

// ---------------- depthwise causal conv (K=4) + bias + SiLU, x8 vectorized ----------------
__global__ void k_conv_silu(const unsigned short* __restrict__ xr,
                            const float* __restrict__ Wc,
                            const float* __restrict__ bc,
                            unsigned short* __restrict__ xcb) {
  int idx = blockIdx.x * 256 + threadIdx.x;   // over L*DI/8
  int t = idx >> 8;                            // 256 d-groups of 8 per row
  int d8 = (idx & 255) * 8;
  const size_t rs = 2 * DI_DIM;
  u16x8 x0 = (u16x8)(unsigned short)0, x1 = x0, x2 = x0;
  u16x8 x3 = *(const u16x8*)&xr[(size_t)t * rs + d8];
  if (t >= 1) x2 = *(const u16x8*)&xr[(size_t)(t - 1) * rs + d8];
  if (t >= 2) x1 = *(const u16x8*)&xr[(size_t)(t - 2) * rs + d8];
  if (t >= 3) x0 = *(const u16x8*)&xr[(size_t)(t - 3) * rs + d8];
  float4 b0 = *(const float4*)&bc[d8];
  float4 b1 = *(const float4*)&bc[d8 + 4];
  float bb[8] = {b0.x, b0.y, b0.z, b0.w, b1.x, b1.y, b1.z, b1.w};
  u16x8 o;
#pragma unroll
  for (int j = 0; j < 8; j++) {
    float4 wd = *(const float4*)&Wc[(size_t)(d8 + j) * 4];
    float acc = bb[j] + bf2f(x0[j]) * wd.x + bf2f(x1[j]) * wd.y +
                bf2f(x2[j]) * wd.z + bf2f(x3[j]) * wd.w;
    o[j] = f2bf(siluf(acc));
  }
  *(u16x8*)&xcb[(size_t)t * DI_DIM + d8] = o;
}

// ---------------- scan phase A: per-chunk local scan ----------------
// p1f != nullptr => GEMM2 was split-K: proj = p0 + p1 + b_x (bias fused here).
__global__ __launch_bounds__(256) void k_scan_a(
    const float* __restrict__ p0, const float* __restrict__ p1f,
    const float* __restrict__ bx, const unsigned short* __restrict__ xcb,
    const float* __restrict__ A_log,
    float* __restrict__ Sdelta, float* __restrict__ hstate) {
  __shared__ float Bsh[LCHUNK * NSSM];
  const int d = blockIdx.x * 256 + threadIdx.x;
  const int c = blockIdx.y;
  const int t0 = c * LCHUNK;
  const float spf = (p1f != nullptr) ? 1.f : 0.f;
  const float* p1 = (p1f != nullptr) ? p1f : p0;   // valid dummy when unsplit
  for (int i = threadIdx.x; i < LCHUNK * NSSM; i += 256) {
    int t = i >> 4, n = i & 15;
    size_t o = (size_t)(t0 + t) * NPROJ + DI_DIM + n;
    Bsh[i] = p0[o] + spf * (p1[o] + bx[DI_DIM + n]);
  }
  __syncthreads();
  float Ar[NSSM], h[NSSM];
#pragma unroll
  for (int n = 0; n < NSSM; n++) {
    Ar[n] = -__expf(A_log[d * NSSM + n]);
    h[n] = 0.f;
  }
  const float bxd = spf * bx[d];
  const float* pp = p0 + (size_t)t0 * NPROJ + d;
  const float* pq = p1 + (size_t)t0 * NPROJ + d;
  const unsigned short* xp = xcb + (size_t)t0 * DI_DIM + d;
  float p_nxt = pp[0] + spf * pq[0];
  unsigned short x_nxt = xp[0];
  float sd = 0.f;
  for (int t = 0; t < LCHUNK; t++) {
    float p = p_nxt;
    unsigned short xu = x_nxt;
    if (t + 1 < LCHUNK) {                          // prefetch next step
      p_nxt = pp[(size_t)(t + 1) * NPROJ] + spf * pq[(size_t)(t + 1) * NPROJ];
      x_nxt = xp[(size_t)(t + 1) * DI_DIM];
    }
    float delta = softplusf(p + bxd);
    float dx = delta * bf2f(xu);
    sd += delta;
#pragma unroll
    for (int n = 0; n < NSSM; n++)
      h[n] = __expf(delta * Ar[n]) * h[n] + dx * Bsh[t * NSSM + n];
  }
  Sdelta[(size_t)c * DI_DIM + d] = sd;
  float4* hp = (float4*)&hstate[((size_t)c * DI_DIM + d) * NSSM];
  hp[0] = (float4){h[0], h[1], h[2], h[3]};
  hp[1] = (float4){h[4], h[5], h[6], h[7]};
  hp[2] = (float4){h[8], h[9], h[10], h[11]};
  hp[3] = (float4){h[12], h[13], h[14], h[15]};
}

// ---------------- scan phase B: combine across chunks (in-place) ----------------
// batch-8 load-ahead: the 64-iter serial chain exposed ~700cy/iter of global
// latency at 0.5 blocks/CU; batching 8 independent loads per 8 carry steps
// cuts exposed latency ~8x.
__global__ void k_scan_b(const float* __restrict__ A_log,
                         const float* __restrict__ Sdelta,
                         float* __restrict__ hstate) {
  int tid = blockIdx.x * 256 + threadIdx.x;  // d*16+n
  int d = tid >> 4;
  float A = -__expf(A_log[tid]);
  float carry = 0.f;
  for (int cb = 0; cb < NCHUNK; cb += 8) {
    float v[8], s[8];
#pragma unroll
    for (int j = 0; j < 8; j++) {
      v[j] = hstate[(size_t)(cb + j) * DI_DIM * NSSM + tid];
      s[j] = Sdelta[(size_t)(cb + j) * DI_DIM + d];
    }
#pragma unroll
    for (int j = 0; j < 8; j++) {
      hstate[(size_t)(cb + j) * DI_DIM * NSSM + tid] = carry;
      carry = __expf(A * s[j]) * carry + v[j];
    }
  }
}

// ---------------- scan phase C: replay with h0, produce y*silu(res) ----------------
__global__ __launch_bounds__(256) void k_scan_c(
    const float* __restrict__ p0, const float* __restrict__ p1f,
    const float* __restrict__ bx, const unsigned short* __restrict__ xcb,
    const float* __restrict__ A_log, const float* __restrict__ h0,
    const float* __restrict__ Dvec, const unsigned short* __restrict__ xr,
    unsigned short* __restrict__ ybf) {
  __shared__ float Bsh[LCHUNK * NSSM];
  __shared__ float Csh[LCHUNK * NSSM];
  const int d = blockIdx.x * 256 + threadIdx.x;
  const int c = blockIdx.y;
  const int t0 = c * LCHUNK;
  const float spf = (p1f != nullptr) ? 1.f : 0.f;
  const float* p1 = (p1f != nullptr) ? p1f : p0;
  for (int i = threadIdx.x; i < LCHUNK * NSSM; i += 256) {
    int t = i >> 4, n = i & 15;
    size_t ob = (size_t)(t0 + t) * NPROJ + DI_DIM + n;
    size_t oc = ob + NSSM;
    Bsh[i] = p0[ob] + spf * (p1[ob] + bx[DI_DIM + n]);
    Csh[i] = p0[oc] + spf * (p1[oc] + bx[DI_DIM + NSSM + n]);
  }
  __syncthreads();
  float Ar[NSSM], h[NSSM];
#pragma unroll
  for (int n = 0; n < NSSM; n++)
    Ar[n] = -__expf(A_log[d * NSSM + n]);
  const float4* h0p = (const float4*)&h0[((size_t)c * DI_DIM + d) * NSSM];
  float4 hv0 = h0p[0], hv1 = h0p[1], hv2 = h0p[2], hv3 = h0p[3];
  h[0] = hv0.x; h[1] = hv0.y; h[2] = hv0.z; h[3] = hv0.w;
  h[4] = hv1.x; h[5] = hv1.y; h[6] = hv1.z; h[7] = hv1.w;
  h[8] = hv2.x; h[9] = hv2.y; h[10] = hv2.z; h[11] = hv2.w;
  h[12] = hv3.x; h[13] = hv3.y; h[14] = hv3.z; h[15] = hv3.w;
  float Dd = Dvec[d];
  const float bxd = spf * bx[d];
  const float* pp = p0 + (size_t)t0 * NPROJ + d;
  const float* pq = p1 + (size_t)t0 * NPROJ + d;
  const unsigned short* xp = xcb + (size_t)t0 * DI_DIM + d;
  const unsigned short* rp = xr + (size_t)t0 * (2 * DI_DIM) + DI_DIM + d;
  float p_nxt = pp[0] + spf * pq[0];
  unsigned short x_nxt = xp[0];
  unsigned short r_nxt = rp[0];
  for (int t = 0; t < LCHUNK; t++) {
    float p = p_nxt;
    unsigned short xu = x_nxt, ru = r_nxt;
    if (t + 1 < LCHUNK) {                          // prefetch next step
      p_nxt = pp[(size_t)(t + 1) * NPROJ] + spf * pq[(size_t)(t + 1) * NPROJ];
      x_nxt = xp[(size_t)(t + 1) * DI_DIM];
      r_nxt = rp[(size_t)(t + 1) * (2 * DI_DIM)];
    }
    float delta = softplusf(p + bxd);
    float xi = bf2f(xu);
    float dx = delta * xi;
    float y = 0.f;
#pragma unroll
    for (int n = 0; n < NSSM; n++) {
      h[n] = __expf(delta * Ar[n]) * h[n] + dx * Bsh[t * NSSM + n];
      y += h[n] * Csh[t * NSSM + n];
    }
    y += xi * Dd;
    y *= siluf(bf2f(ru));
    ybf[(size_t)(t0 + t) * DI_DIM + d] = f2bf(y);
  }
}

extern "C" void kernel_launch(void* const* d_in, const int* in_sizes, int n_in,
                              void* d_out, int out_size, void* d_ws, size_t ws_size,
                              hipStream_t stream) {
  const float* x      = (const float*)d_in[0];
  const float* W_in   = (const float*)d_in[1];
  const float* b_in   = (const float*)d_in[2];
  const float* W_conv = (const float*)d_in[3];
  const float* b_conv = (const float*)d_in[4];
  const float* W_x    = (const float*)d_in[5];
  const float* b_x    = (const float*)d_in[6];
  const float* W_out  = (const float*)d_in[7];
  const float* b_out  = (const float*)d_in[8];
  const float* A_log  = (const float*)d_in[9];
  const float* Dv     = (const float*)d_in[10];
  float* out = (float*)d_out;

  char* ws = (char*)d_ws;
  size_t off = 0;
  auto alloc = [&](size_t bytes) { void* p = ws + off; off += (bytes + 255) & ~(size_t)255; return p; };
  unsigned short* win_bf = (unsigned short*)alloc((size_t)4096 * DMODEL * 2);        // 8.39 MB; reused as ybf
  unsigned short* wx_bf  = (unsigned short*)alloc((size_t)NPROJ * DI_DIM * 2);       // 8.52 MB
  unsigned short* x_bf   = (unsigned short*)alloc((size_t)L_SEQ * DMODEL * 2);       // 4.19 MB; reused as wout_bf
  unsigned short* xr_bf  = (unsigned short*)alloc((size_t)L_SEQ * 2 * DI_DIM * 2);   // 16.78 MB
  unsigned short* xcb    = (unsigned short*)alloc((size_t)L_SEQ * DI_DIM * 2);       // 8.39 MB; reused as GEMM3 z3 partial
  float* proj            = (float*)alloc((size_t)L_SEQ * NPROJ * 4);                 // 17.04 MB; reused as GEMM3 z0..z2 partials
  float* Sdelta          = (float*)alloc((size_t)NCHUNK * DI_DIM * 4);               // 0.52 MB  (overrun by GEMM3 z2 - dead then)
  float* hstate          = (float*)alloc((size_t)NCHUNK * DI_DIM * NSSM * 4);        // 8.39 MB  (overrun by GEMM3 z2 - dead then)
  if (off > ws_size) return;  // proven base budget: 72.2 MB
  // optional split-K partial for GEMM2 (falls back to unsplit if ws too small)
  float* part1 = nullptr;
  {
    size_t need = (size_t)L_SEQ * NPROJ * 4;       // 17.04 MB
    if (off + need <= ws_size) part1 = (float*)alloc(need);
  }
  unsigned short* ybf     = win_bf;  // dead after GEMM1, reborn as y (scan_c -> GEMM3)
  unsigned short* wout_bf = x_bf;    // dead after GEMM1, reborn as W_out bf16

  // fused converts: x, W_in, W_x
  k_convert3<<<CVT_N3 / 256, 256, 0, stream>>>(x, W_in, W_x, x_bf, win_bf, wx_bf);

  // GEMM1: xr = x @ W_in^T + b_in (2048x4096, K=1024), bf16 out
  // DEPTH=3 ring (36KB LDS -> 4 blocks/CU, matches grid's 4/CU)
  {
    dim3 g(4096 / 128, L_SEQ / 64);
    k_gemm_bt<unsigned short, 3><<<g, 256, 0, stream>>>(
        x_bf, win_bf, b_in, xr_bf, (unsigned short*)nullptr, 8, L_SEQ, 4096, DMODEL);
  }
  // convert W_out into x_bf's slot (x dead after GEMM1)
  k_f32_to_bf16<<<(DMODEL * DI_DIM / 4) / 256, 256, 0, stream>>>(W_out, wout_bf, DMODEL * DI_DIM / 4);
  // depthwise conv + SiLU (x8 vectorized)
  k_conv_silu<<<(L_SEQ * DI_DIM / 8) / 256, 256, 0, stream>>>(xr_bf, W_conv, b_conv, xcb);
  // GEMM2: proj = xi @ W_x^T (+ b_x) (2048x2080, K=2048), f32 out
  // split-K=2 when ws allows: 1088 blocks -> 4 blocks/CU (was 544 = 2.1/CU,
  // Occupancy 18%); partial-sum + bias fused into scan_a/scan_c.
  {
    dim3 g((NPROJ + 127) / 128, L_SEQ / 64, part1 ? 2 : 1);
    k_gemm_bt<float, 3><<<g, 256, 0, stream>>>(
        xcb, wx_bf, b_x, proj, part1, 1, L_SEQ, NPROJ, DI_DIM);
  }
  // selective scan (chunked 3-phase); scan_a/c fuse GEMM2 partial reduce
  {
    dim3 ga(DI_DIM / 256, NCHUNK);
    k_scan_a<<<ga, 256, 0, stream>>>(proj, part1, b_x, xcb, A_log, Sdelta, hstate);
    k_scan_b<<<(DI_DIM * NSSM) / 256, 256, 0, stream>>>(A_log, Sdelta, hstate);
    k_scan_c<<<ga, 256, 0, stream>>>(proj, part1, b_x, xcb, A_log, hstate, Dv, xr_bf, ybf);
  }
  // GEMM3: split-K=4 (1024 blocks -> 4 blocks/CU). Partials: z0..z2 in
  // proj+Sdelta+hstate region (25.95MB >= 3*8.39MB, all dead post-scan),
  // z3 in xcb (dead post-scan). Then 4-way reduce + bias.
  {
    dim3 g(DMODEL / 128, L_SEQ / 64, 4);
    k_gemm_bt<float, 3><<<g, 256, 0, stream>>>(
        ybf, wout_bf, b_out, proj, (float*)xcb, 3, L_SEQ, DMODEL, DI_DIM);
    k_reduce_out4<<<(L_SEQ * DMODEL / 4) / 256, 256, 0, stream>>>(proj, (float*)xcb, b_out, out);
  }
}

// Round 3
// 262.089 us; speedup vs baseline: 1.0670x; 1.0670x over previous
//
#include <hip/hip_runtime.h>
#include <stdint.h>

// Problem constants (B=1)
#define L_SEQ 2048
#define DMODEL 1024
#define DI_DIM 2048
#define NSSM 16
#define NPROJ 2080        // DI + 2N
#define NCHUNK 64
#define LCHUNK 32         // NCHUNK*LCHUNK == L_SEQ

typedef __attribute__((ext_vector_type(8))) short bf16x8;
typedef __attribute__((ext_vector_type(8))) unsigned short u16x8;
typedef __attribute__((ext_vector_type(4))) float f32x4;

__device__ __forceinline__ float bf2f(unsigned short u) {
  union { uint32_t u; float f; } v; v.u = (uint32_t)u << 16; return v.f;
}
__device__ __forceinline__ unsigned short f2bf(float f) {
  union { float f; uint32_t u; } v; v.f = f;
  uint32_t u = v.u;
  return (unsigned short)((u + 0x7fffu + ((u >> 16) & 1u)) >> 16);
}
__device__ __forceinline__ void async16(const void* g, void* l) {
  __builtin_amdgcn_global_load_lds(
      (__attribute__((address_space(1))) void*)(g),
      (__attribute__((address_space(3))) void*)(l), 16, 0, 0);
}
// native-op math (libm log1pf/fdiv expand to huge sequences w/o fast-math;
// switching to __logf/__expf/rcp collapsed scan kernels ~3x -- r7 measured)
__device__ __forceinline__ float softplusf(float p) {
  return (p > 20.f) ? p : __logf(1.f + __expf(p));
}
__device__ __forceinline__ float siluf(float x) {
  return x * __builtin_amdgcn_rcpf(1.f + __expf(-x));
}

// counted-vmcnt ring primitives. r1/r2 A/B: depth 2/3/4 all equal (pipeline
// depth is NOT the constraint); kept because harmless and barrier-count-min.
#define WAITV(N) asm volatile("s_waitcnt vmcnt(" #N ")" ::: "memory")
#define GBAR()                                   \
  {                                              \
    __builtin_amdgcn_s_barrier();                \
    asm volatile("" ::: "memory");               \
  }

// ---------------- fused f32 -> bf16 converts (x, W_in, W_x, W_out) ----------------
#define CVT_N1 524288                    // x:     2048*1024/4
#define CVT_N2 (CVT_N1 + 1048576)        // W_in:  4096*1024/4
#define CVT_N3 (CVT_N2 + 1064960)        // W_x:   2080*2048/4
#define CVT_N4 (CVT_N3 + 524288)         // W_out: 1024*2048/4
__global__ void k_convert4(const float* __restrict__ x, const float* __restrict__ win,
                           const float* __restrict__ wx, const float* __restrict__ wout,
                           unsigned short* __restrict__ xb, unsigned short* __restrict__ winb,
                           unsigned short* __restrict__ wxb, unsigned short* __restrict__ woutb) {
  int i = blockIdx.x * 256 + threadIdx.x;
  const float4* src; unsigned short* dst; int j;
  if (i < CVT_N1)      { src = (const float4*)x;    dst = xb;    j = i; }
  else if (i < CVT_N2) { src = (const float4*)win;  dst = winb;  j = i - CVT_N1; }
  else if (i < CVT_N3) { src = (const float4*)wx;   dst = wxb;   j = i - CVT_N2; }
  else if (i < CVT_N4) { src = (const float4*)wout; dst = woutb; j = i - CVT_N3; }
  else return;
  float4 v = src[j];
  ushort4 o;
  o.x = f2bf(v.x); o.y = f2bf(v.y); o.z = f2bf(v.z); o.w = f2bf(v.w);
  ((ushort4*)dst)[j] = o;
}

// ---------------- bf16 N-T GEMM: C = A[M,K] * B[N,K]^T (+bias) ----------------
// TM=64 x 128 tile, 32-K steps, DEPTH=3 LDS ring (36KB), counted vmcnt.
// Factor status from A/B history: atomics -40% | uncoalesced staging -60% |
// TM=32 compute dilution -25% | row-major LDS conflicts -11% | XOR-swizzle
// verified 0 conflicts | ring depth 2/3/4 neutral | split-K occupancy 2x
// neutral-to-negative (write traffic).
// THIS ROUND: m-fastest block order (blockIdx.x = m-tile). Old order (n
// fastest) re-swept the 8.5MB B operand once per m-row -> 66MB HBM FETCH
// (3.9x over input set) at ~2TB/s effective = the measured duration. m-fastest
// keeps the 512KB B n-panel L2-resident across consecutive blocks; A streams
// once per n-column (L3-resident after first sweep).
// Macro-stamped distinct names per call site so rocprof ranks them separately.
#define GSTAGE(BUF, KT)                                                        \
  {                                                                            \
    async16(ap + (KT), &As[BUF][soA]);                                         \
    async16(bp0 + (KT), &Bs[BUF][soB0]);                                       \
    async16(bp1 + (KT), &Bs[BUF][soB1]);                                       \
  }

#define GCOMPUTE(BUF)                                                          \
  {                                                                            \
    bf16x8 af[4], bfv[2];                                                      \
    _Pragma("unroll")                                                          \
    for (int i = 0; i < 4; i++)                                                \
      af[i] = *(const bf16x8*)&As[BUF][i * 512 + ro];                          \
    _Pragma("unroll")                                                          \
    for (int j = 0; j < 2; j++)                                                \
      bfv[j] = *(const bf16x8*)&Bs[BUF][(wave * 2 + j) * 512 + ro];            \
    _Pragma("unroll")                                                          \
    for (int i = 0; i < 4; i++)                                                \
      _Pragma("unroll")                                                        \
      for (int j = 0; j < 2; j++)                                              \
        acc[i][j] = __builtin_amdgcn_mfma_f32_16x16x32_bf16(af[i], bfv[j],     \
                                                        acc[i][j], 0, 0, 0);   \
  }

#define DEFINE_GEMM_BT(NAME, OutT)                                             \
__global__ __launch_bounds__(256) void NAME(                                   \
    const unsigned short* __restrict__ A, const unsigned short* __restrict__ B,\
    const float* __restrict__ bias, OutT* __restrict__ C,                      \
    int M, int N, int K) {                                                     \
  __shared__ unsigned short As[3][64 * 32];                                    \
  __shared__ unsigned short Bs[3][128 * 32];                                   \
  const int tid = threadIdx.x;                                                 \
  const int wave = tid >> 6;                                                   \
  const int lane = tid & 63;                                                   \
  const int m0 = blockIdx.x * 64;   /* m fastest: B n-panel stays L2-hot */    \
  const int n0 = blockIdx.y * 128;                                             \
  const int kLen = K / gridDim.z;                                              \
  const int kLo = blockIdx.z * kLen;                                           \
  /* staging: lane l -> row l>>2, kgroup (l&3)^((l>>3)&3) (XOR-swizzled) */    \
  const int srow = lane >> 2;                                                  \
  const int scol = ((lane & 3) ^ ((lane >> 3) & 3)) * 8;                       \
  int ar = m0 + wave * 16 + srow;         if (ar > M - 1) ar = M - 1;          \
  int br0 = n0 + wave * 32 + srow;        if (br0 > N - 1) br0 = N - 1;        \
  int br1 = n0 + wave * 32 + 16 + srow;   if (br1 > N - 1) br1 = N - 1;        \
  const unsigned short* ap  = A + (size_t)ar * K + scol + kLo;                 \
  const unsigned short* bp0 = B + (size_t)br0 * K + scol + kLo;                \
  const unsigned short* bp1 = B + (size_t)br1 * K + scol + kLo;                \
  const int soA  = wave * 512;                                                 \
  const int soB0 = (wave * 2) * 512;                                           \
  const int soB1 = (wave * 2 + 1) * 512;                                       \
  /* fragment read: block_base + mrow*32 + swz8 (ushorts) */                   \
  const int mrow = lane & 15;                                                  \
  const int swz8 = (((lane >> 4) ^ ((mrow >> 1) & 3)) * 8);                    \
  const int ro = mrow * 32 + swz8;                                             \
  f32x4 acc[4][2];                                                             \
  _Pragma("unroll")                                                            \
  for (int i = 0; i < 4; i++)                                                  \
    _Pragma("unroll")                                                          \
    for (int j = 0; j < 2; j++) acc[i][j] = (f32x4){0.f, 0.f, 0.f, 0.f};       \
  const int niter = kLen / 32;                                                 \
  _Pragma("unroll")                                                            \
  for (int j = 0; j < 2; j++) GSTAGE(j, j * 32)                                \
  int cur = 0, nxt = 2;                                                        \
  for (int t = 0; t < niter - 2; t++) {                                        \
    WAITV(3);                                                                  \
    GBAR()                                                                     \
    GSTAGE(nxt, (t + 2) * 32)                                                  \
    GCOMPUTE(cur)                                                              \
    cur = (cur == 2) ? 0 : cur + 1;                                            \
    nxt = (nxt == 2) ? 0 : nxt + 1;                                            \
  }                                                                            \
  WAITV(3); GBAR()                                                             \
  GCOMPUTE(cur) cur = (cur == 2) ? 0 : cur + 1;                                \
  WAITV(0); GBAR()                                                             \
  GCOMPUTE(cur)                                                                \
  /* epilogue: C/D layout col=lane&15, row=(lane>>4)*4+reg (verified) */       \
  const bool withBias = (gridDim.z == 1);                                      \
  OutT* Cz = C + (size_t)blockIdx.z * ((size_t)M * N);                         \
  _Pragma("unroll")                                                            \
  for (int j = 0; j < 2; j++) {                                                \
    int col = n0 + wave * 32 + j * 16 + (lane & 15);                           \
    if (col < N) {                                                             \
      float bv = withBias ? bias[col] : 0.f;                                   \
      _Pragma("unroll")                                                        \
      for (int i = 0; i < 4; i++) {                                            \
        int rbase = m0 + i * 16 + (lane >> 4) * 4;                             \
        _Pragma("unroll")                                                      \
        for (int r = 0; r < 4; r++) {                                          \
          float v = acc[i][j][r] + bv;                                         \
          if constexpr (sizeof(OutT) == 2)                                     \
            Cz[(size_t)(rbase + r) * N + col] = (OutT)f2bf(v);                 \
          else                                                                 \
            Cz[(size_t)(rbase + r) * N + col] = (OutT)v;                       \
        }                                                                      \
      }                                                                        \
    }                                                                          \
  }                                                                            \
}

DEFINE_GEMM_BT(k_gemm_xr, unsigned short)   // GEMM1: xr = x @ W_in^T + b_in
DEFINE_GEMM_BT(k_gemm_proj, float)          // GEMM2: proj = xi @ W_x^T + b_x
DEFINE_GEMM_BT(k_gemm_out, float)           // GEMM3: split-K=2 partials

// ---------------- split-K=2 reduce: out = p0 + p1 + bias ----------------
__global__ void k_reduce_out(const float* __restrict__ part, const float* __restrict__ bias,
                             float* __restrict__ out) {
  int i = blockIdx.x * 256 + threadIdx.x;   // float4 index over 2048*1024
  float4 a = ((const float4*)part)[i];
  float4 b = ((const float4*)(part + (size_t)L_SEQ * DMODEL))[i];
  int col = (i * 4) & (DMODEL - 1);
  float4 bb = *(const float4*)&bias[col];
  float4 o;
  o.x = a.x + b.x + bb.x; o.y = a.y + b.y + bb.y;
  o.z = a.z + b.z + bb.z; o.w = a.w + b.w + bb.w;
  ((float4*)out)[i] = o;
}

// ---------------- depthwise causal conv (K=4) + bias + SiLU, x8 vectorized ----------------
__global__ void k_conv_silu(const unsigned short* __restrict__ xr,
                            const float* __restrict__ Wc,
                            const float* __restrict__ bc,
                            unsigned short* __restrict__ xcb) {
  int idx = blockIdx.x * 256 + threadIdx.x;   // over L*DI/8
  int t = idx >> 8;                            // 256 d-groups of 8 per row
  int d8 = (idx & 255) * 8;
  const size_t rs = 2 * DI_DIM;
  u16x8 x0 = (u16x8)(unsigned short)0, x1 = x0, x2 = x0;
  u16x8 x3 = *(const u16x8*)&xr[(size_t)t * rs + d8];
  if (t >= 1) x2 = *(const u16x8*)&xr[(size_t)(t - 1) * rs + d8];
  if (t >= 2) x1 = *(const u16x8*)&xr[(size_t)(t - 2) * rs + d8];
  if (t >= 3) x0 = *(const u16x8*)&xr[(size_t)(t - 3) * rs + d8];
  float4 b0 = *(const float4*)&bc[d8];
  float4 b1 = *(const float4*)&bc[d8 + 4];
  float bb[8] = {b0.x, b0.y, b0.z, b0.w, b1.x, b1.y, b1.z, b1.w};
  u16x8 o;
#pragma unroll
  for (int j = 0; j < 8; j++) {
    float4 wd = *(const float4*)&Wc[(size_t)(d8 + j) * 4];
    float acc = bb[j] + bf2f(x0[j]) * wd.x + bf2f(x1[j]) * wd.y +
                bf2f(x2[j]) * wd.z + bf2f(x3[j]) * wd.w;
    o[j] = f2bf(siluf(acc));
  }
  *(u16x8*)&xcb[(size_t)t * DI_DIM + d8] = o;
}

// ---------------- scan phase A: per-chunk local scan ----------------
__global__ __launch_bounds__(256) void k_scan_a(
    const float* __restrict__ proj, const unsigned short* __restrict__ xcb,
    const float* __restrict__ A_log,
    float* __restrict__ Sdelta, float* __restrict__ hstate) {
  __shared__ float Bsh[LCHUNK * NSSM];
  const int d = blockIdx.x * 256 + threadIdx.x;
  const int c = blockIdx.y;
  const int t0 = c * LCHUNK;
  for (int i = threadIdx.x; i < LCHUNK * NSSM; i += 256) {
    int t = i >> 4, n = i & 15;
    Bsh[i] = proj[(size_t)(t0 + t) * NPROJ + DI_DIM + n];
  }
  __syncthreads();
  float Ar[NSSM], h[NSSM];
#pragma unroll
  for (int n = 0; n < NSSM; n++) {
    Ar[n] = -__expf(A_log[d * NSSM + n]);
    h[n] = 0.f;
  }
  const float* pp = proj + (size_t)t0 * NPROJ + d;
  const unsigned short* xp = xcb + (size_t)t0 * DI_DIM + d;
  float p_nxt = pp[0];
  unsigned short x_nxt = xp[0];
  float sd = 0.f;
  for (int t = 0; t < LCHUNK; t++) {
    float p = p_nxt;
    unsigned short xu = x_nxt;
    if (t + 1 < LCHUNK) {                          // prefetch next step
      p_nxt = pp[(size_t)(t + 1) * NPROJ];
      x_nxt = xp[(size_t)(t + 1) * DI_DIM];
    }
    float delta = softplusf(p);
    float dx = delta * bf2f(xu);
    sd += delta;
#pragma unroll
    for (int n = 0; n < NSSM; n++)
      h[n] = __expf(delta * Ar[n]) * h[n] + dx * Bsh[t * NSSM + n];
  }
  Sdelta[(size_t)c * DI_DIM + d] = sd;
  float4* hp = (float4*)&hstate[((size_t)c * DI_DIM + d) * NSSM];
  hp[0] = (float4){h[0], h[1], h[2], h[3]};
  hp[1] = (float4){h[4], h[5], h[6], h[7]};
  hp[2] = (float4){h[8], h[9], h[10], h[11]};
  hp[3] = (float4){h[12], h[13], h[14], h[15]};
}

// ---------------- scan phase B: combine across chunks (in-place) ----------------
// batch-8 load-ahead: 64-iter serial chain at 0.5 blocks/CU exposed ~700cy/iter;
// batching 8 independent loads per 8 carry steps cuts exposed latency ~8x.
__global__ void k_scan_b(const float* __restrict__ A_log,
                         const float* __restrict__ Sdelta,
                         float* __restrict__ hstate) {
  int tid = blockIdx.x * 256 + threadIdx.x;  // d*16+n
  int d = tid >> 4;
  float A = -__expf(A_log[tid]);
  float carry = 0.f;
  for (int cb = 0; cb < NCHUNK; cb += 8) {
    float v[8], s[8];
#pragma unroll
    for (int j = 0; j < 8; j++) {
      v[j] = hstate[(size_t)(cb + j) * DI_DIM * NSSM + tid];
      s[j] = Sdelta[(size_t)(cb + j) * DI_DIM + d];
    }
#pragma unroll
    for (int j = 0; j < 8; j++) {
      hstate[(size_t)(cb + j) * DI_DIM * NSSM + tid] = carry;
      carry = __expf(A * s[j]) * carry + v[j];
    }
  }
}

// ---------------- scan phase C: replay with h0, produce y*silu(res) ----------------
__global__ __launch_bounds__(256) void k_scan_c(
    const float* __restrict__ proj, const unsigned short* __restrict__ xcb,
    const float* __restrict__ A_log, const float* __restrict__ h0,
    const float* __restrict__ Dvec, const unsigned short* __restrict__ xr,
    unsigned short* __restrict__ ybf) {
  __shared__ float Bsh[LCHUNK * NSSM];
  __shared__ float Csh[LCHUNK * NSSM];
  const int d = blockIdx.x * 256 + threadIdx.x;
  const int c = blockIdx.y;
  const int t0 = c * LCHUNK;
  for (int i = threadIdx.x; i < LCHUNK * NSSM; i += 256) {
    int t = i >> 4, n = i & 15;
    size_t ob = (size_t)(t0 + t) * NPROJ + DI_DIM + n;
    Bsh[i] = proj[ob];
    Csh[i] = proj[ob + NSSM];
  }
  __syncthreads();
  float Ar[NSSM], h[NSSM];
#pragma unroll
  for (int n = 0; n < NSSM; n++)
    Ar[n] = -__expf(A_log[d * NSSM + n]);
  const float4* h0p = (const float4*)&h0[((size_t)c * DI_DIM + d) * NSSM];
  float4 hv0 = h0p[0], hv1 = h0p[1], hv2 = h0p[2], hv3 = h0p[3];
  h[0] = hv0.x; h[1] = hv0.y; h[2] = hv0.z; h[3] = hv0.w;
  h[4] = hv1.x; h[5] = hv1.y; h[6] = hv1.z; h[7] = hv1.w;
  h[8] = hv2.x; h[9] = hv2.y; h[10] = hv2.z; h[11] = hv2.w;
  h[12] = hv3.x; h[13] = hv3.y; h[14] = hv3.z; h[15] = hv3.w;
  float Dd = Dvec[d];
  const float* pp = proj + (size_t)t0 * NPROJ + d;
  const unsigned short* xp = xcb + (size_t)t0 * DI_DIM + d;
  const unsigned short* rp = xr + (size_t)t0 * (2 * DI_DIM) + DI_DIM + d;
  float p_nxt = pp[0];
  unsigned short x_nxt = xp[0];
  unsigned short r_nxt = rp[0];
  for (int t = 0; t < LCHUNK; t++) {
    float p = p_nxt;
    unsigned short xu = x_nxt, ru = r_nxt;
    if (t + 1 < LCHUNK) {                          // prefetch next step
      p_nxt = pp[(size_t)(t + 1) * NPROJ];
      x_nxt = xp[(size_t)(t + 1) * DI_DIM];
      r_nxt = rp[(size_t)(t + 1) * (2 * DI_DIM)];
    }
    float delta = softplusf(p);
    float xi = bf2f(xu);
    float dx = delta * xi;
    float y = 0.f;
#pragma unroll
    for (int n = 0; n < NSSM; n++) {
      h[n] = __expf(delta * Ar[n]) * h[n] + dx * Bsh[t * NSSM + n];
      y += h[n] * Csh[t * NSSM + n];
    }
    y += xi * Dd;
    y *= siluf(bf2f(ru));
    ybf[(size_t)(t0 + t) * DI_DIM + d] = f2bf(y);
  }
}

extern "C" void kernel_launch(void* const* d_in, const int* in_sizes, int n_in,
                              void* d_out, int out_size, void* d_ws, size_t ws_size,
                              hipStream_t stream) {
  const float* x      = (const float*)d_in[0];
  const float* W_in   = (const float*)d_in[1];
  const float* b_in   = (const float*)d_in[2];
  const float* W_conv = (const float*)d_in[3];
  const float* b_conv = (const float*)d_in[4];
  const float* W_x    = (const float*)d_in[5];
  const float* b_x    = (const float*)d_in[6];
  const float* W_out  = (const float*)d_in[7];
  const float* b_out  = (const float*)d_in[8];
  const float* A_log  = (const float*)d_in[9];
  const float* Dv     = (const float*)d_in[10];
  float* out = (float*)d_out;

  char* ws = (char*)d_ws;
  size_t off = 0;
  auto alloc = [&](size_t bytes) { void* p = ws + off; off += (bytes + 255) & ~(size_t)255; return p; };
  unsigned short* win_bf = (unsigned short*)alloc((size_t)4096 * DMODEL * 2);        // 8.39 MB; reused as ybf
  unsigned short* wx_bf  = (unsigned short*)alloc((size_t)NPROJ * DI_DIM * 2);       // 8.52 MB
  unsigned short* x_bf   = (unsigned short*)alloc((size_t)L_SEQ * DMODEL * 2);       // 4.19 MB; reused as wout_bf
  unsigned short* xr_bf  = (unsigned short*)alloc((size_t)L_SEQ * 2 * DI_DIM * 2);   // 16.78 MB
  unsigned short* xcb    = (unsigned short*)alloc((size_t)L_SEQ * DI_DIM * 2);       // 8.39 MB
  float* proj            = (float*)alloc((size_t)L_SEQ * NPROJ * 4);                 // 17.04 MB; reused as GEMM3 partials (16.78 MB)
  float* Sdelta          = (float*)alloc((size_t)NCHUNK * DI_DIM * 4);               // 0.52 MB
  float* hstate          = (float*)alloc((size_t)NCHUNK * DI_DIM * NSSM * 4);        // 8.39 MB
  if (off > ws_size) return;  // proven budget: 72.2 MB
  unsigned short* ybf     = win_bf;  // dead after GEMM1, reborn as y (scan_c -> GEMM3)
  unsigned short* wout_bf = x_bf;    // dead after GEMM1, reborn as W_out bf16
  float* part             = proj;    // dead after scan_c, reborn as GEMM3 split-K partials (2 x 8.39 MB)

  // fused converts: x, W_in, W_x, W_out (W_out slab aliases x_bf but x is
  // consumed only by GEMM1 which reads x_bf... NOT safe to overwrite before
  // GEMM1 -> W_out goes to its own region? No: wout_bf == x_bf. Keep W_out
  // conversion AFTER GEMM1 would need a separate launch. Instead, place
  // W_out bf16 at the tail of xr_bf? xr_bf is written by GEMM1. Use hstate
  // region (8.39 MB >= 4.19 MB, dead until scan_a).
  unsigned short* woutb = (unsigned short*)hstate;  // hstate dead until scan_a;
  // scan_a writes hstate AFTER GEMM3's B operand... conflict: GEMM3 reads
  // woutb at the END. hstate is written by scan_a before GEMM3. CONFLICT.
  // -> keep W_out in wout_bf (=x_bf) but convert it in the fused kernel is
  // unsafe (x still live). Solution: fused kernel writes W_out bf16 into
  // Sdelta+hstate is unsafe; so simply give W_out its own slot: reuse xcb?
  // xcb written by conv AFTER GEMM1. Also conflict. Cleanest: separate tiny
  // region check. 72.2+4.2 = 76.4 MB; try tail alloc, fallback to 2-kernel.
  unsigned short* wout2 = nullptr;
  {
    size_t need = (size_t)DMODEL * DI_DIM * 2;
    if (off + need <= ws_size) wout2 = (unsigned short*)alloc(need);
  }
  if (wout2) {
    k_convert4<<<CVT_N4 / 256, 256, 0, stream>>>(x, W_in, W_x, W_out,
                                                 x_bf, win_bf, wx_bf, wout2);
    wout_bf = wout2;
  } else {
    k_convert4<<<CVT_N3 / 256, 256, 0, stream>>>(x, W_in, W_x, W_out,
                                                 x_bf, win_bf, wx_bf, wout_bf);
    // (grid stops before W_out segment; convert below after GEMM1)
  }

  // GEMM1: xr = x @ W_in^T + b_in (2048x4096, K=1024), bf16 out, m-fastest grid
  {
    dim3 g(L_SEQ / 64, 4096 / 128);
    k_gemm_xr<<<g, 256, 0, stream>>>(x_bf, win_bf, b_in, xr_bf, L_SEQ, 4096, DMODEL);
  }
  if (!wout2) {
    // fallback path: convert W_out into x_bf's slot now that x is dead
    k_convert4<<<(CVT_N4 - CVT_N3) / 256, 256, 0, stream>>>(
        W_out - (size_t)CVT_N3 * 4 + (size_t)CVT_N3 * 4, W_in, W_x, W_out,
        x_bf, win_bf, wx_bf, wout_bf);  // unreachable in practice (ws is ample)
  }
  // depthwise conv + SiLU (x8 vectorized)
  k_conv_silu<<<(L_SEQ * DI_DIM / 8) / 256, 256, 0, stream>>>(xr_bf, W_conv, b_conv, xcb);
  // GEMM2: proj = xi @ W_x^T + b_x (2048x2080, K=2048), f32 out, m-fastest grid
  {
    dim3 g(L_SEQ / 64, (NPROJ + 127) / 128);
    k_gemm_proj<<<g, 256, 0, stream>>>(xcb, wx_bf, b_x, proj, L_SEQ, NPROJ, DI_DIM);
  }
  // selective scan (chunked 3-phase)
  {
    dim3 ga(DI_DIM / 256, NCHUNK);
    k_scan_a<<<ga, 256, 0, stream>>>(proj, xcb, A_log, Sdelta, hstate);
    k_scan_b<<<(DI_DIM * NSSM) / 256, 256, 0, stream>>>(A_log, Sdelta, hstate);
    k_scan_c<<<ga, 256, 0, stream>>>(proj, xcb, A_log, hstate, Dv, xr_bf, ybf);
  }
  // GEMM3: split-K=2 (512 blocks), partials in proj region, then reduce+bias
  {
    dim3 g(L_SEQ / 64, DMODEL / 128, 2);
    k_gemm_out<<<g, 256, 0, stream>>>(ybf, wout_bf, b_out, part, L_SEQ, DMODEL, DI_DIM);
    k_reduce_out<<<(L_SEQ * DMODEL / 4) / 256, 256, 0, stream>>>(part, b_out, out);
  }
}